// Round 4
// baseline (621.148 us; speedup 1.0000x reference)
//
#include <hip/hip_runtime.h>
#include <hip/hip_cooperative_groups.h>
#include <hip/hip_fp16.h>
#include <math.h>

#define FDIM  128
#define L1OUT 16
#define L2DIM 17
#define TR    64      // f-rows per tile in node-transform phase
#define TSTR  129     // tile row stride (odd -> conflict-free column reads)

namespace cg = cooperative_groups;

// one 32-byte fp16 node row (16 halves); align 16 -> 2x global_load_dwordx4
struct __align__(16) H16 { __half2 h[8]; };

__device__ __forceinline__ float lrelu(float v) { return v >= 0.f ? v : 0.1f * v; }

// ============================================================================
// Single cooperative kernel, 4 phases separated by grid.sync():
//   P0: zero deg/ssum
//   P1: node transform A/B (LDS-tiled)  +  degree atomics  + stage L2 weights
//   P2: per-edge MLP -> exp -> segment-sum (softmax max-pass removed:
//       identical ratios; |e_val| <~ 15, far inside fp32 exp range)
//   P3: normalize
// Rationale: R1-R3 totals show ~20-25 us fixed cost per launch dominating;
// 4 launches -> 1. Persistent blocks also hold full residency for the
// latency-bound gather phase (was 33% avg occupancy with dispatch ramp/tail).
// ============================================================================
__global__ __launch_bounds__(256, 4) void fused_gat(
    const int* __restrict__ ind, const float* __restrict__ val,
    const float* __restrict__ f, const float* __restrict__ W1,
    const float* __restrict__ b1, const float* __restrict__ W2,
    const float* __restrict__ b2, const float* __restrict__ Wc,
    const float* __restrict__ bc, float* __restrict__ out,
    H16* __restrict__ A, H16* __restrict__ Bm,
    float* __restrict__ deg, float* __restrict__ ssum,
    int N, int E)
{
    cg::grid_group grid = cg::this_grid();
    __shared__ __align__(16) float smem[TR * TSTR];   // 33 KB -> 4 blocks/CU

    const int t    = threadIdx.x;
    const int gtid = blockIdx.x * 256 + t;
    const int GT   = gridDim.x * 256;

    // ---------------- P0: zero per-node accumulators ----------------
    for (int n = gtid; n < N; n += GT) { deg[n] = 0.f; ssum[n] = 0.f; }
    grid.sync();

    // ---------------- P1a: node transform (A = f@W1_top, B = f@W1_bot, fp16)
    {
        const int ntiles  = (N + TR - 1) / TR;
        const int lane    = t & 63;
        const int w       = t >> 6;                  // wave id 0..3
        const int colbase = (w & 1) * 8;             // cols 0-7 / 8-15
        const int krowoff = (w >> 1) * FDIM;         // A: rows 0-127, B: 128-255
        const float* wbase = W1 + (size_t)krowoff * L1OUT + colbase;

        for (int tb = blockIdx.x; tb < ntiles; tb += gridDim.x) {
            const int base = tb * TR;
            // stage 64 f-rows coalesced into padded LDS tile
#pragma unroll
            for (int q = 0; q < 8; ++q) {
                int i4 = t + 256 * q;                // float4 idx 0..2047
                int r  = i4 >> 5;                    // 32 float4 per row
                int c4 = i4 & 31;
                float4 v = make_float4(0.f, 0.f, 0.f, 0.f);
                if (base + r < N)
                    v = reinterpret_cast<const float4*>(f + (size_t)(base + r) * FDIM)[c4];
                float* d = &smem[r * TSTR + c4 * 4];
                d[0] = v.x; d[1] = v.y; d[2] = v.z; d[3] = v.w;
            }
            __syncthreads();

            float acc[8];
#pragma unroll
            for (int c = 0; c < 8; ++c) acc[c] = 0.f;
            const float* trow = &smem[lane * TSTR];
#pragma unroll 4
            for (int k = 0; k < FDIM; ++k) {
                float x = trow[k];                   // 2-way LDS bcast, free
                // W1 slice: wave-broadcast 16B loads, L1-resident (16 KB)
                float4 w0  = *reinterpret_cast<const float4*>(wbase + (size_t)k * L1OUT);
                float4 w1v = *reinterpret_cast<const float4*>(wbase + (size_t)k * L1OUT + 4);
                acc[0] += x * w0.x;  acc[1] += x * w0.y;
                acc[2] += x * w0.z;  acc[3] += x * w0.w;
                acc[4] += x * w1v.x; acc[5] += x * w1v.y;
                acc[6] += x * w1v.z; acc[7] += x * w1v.w;
            }
            int n = base + lane;
            if (n < N) {
                __align__(16) __half2 h[4];
#pragma unroll
                for (int q = 0; q < 4; ++q)
                    h[q] = __floats2half2_rn(acc[2 * q], acc[2 * q + 1]);
                H16* arr = (w >> 1) ? Bm : A;
                float4* dst = reinterpret_cast<float4*>(
                    reinterpret_cast<char*>(arr + n) + (w & 1) * 16);
                *dst = *reinterpret_cast<float4*>(h);
            }
            __syncthreads();   // tile reused next iteration / overlaid below
        }
    }

    // ---------------- P1b: degree atomics (4 edges/thread) ----------------
    {
        const int E4 = E >> 2;
        for (int q = gtid; q < E4; q += GT) {
            int e = q << 2;
            int4   ii = *reinterpret_cast<const int4*>(ind + e);
            float4 vv = *reinterpret_cast<const float4*>(val + e);
            atomicAdd(&deg[ii.x], fabsf(vv.x));
            atomicAdd(&deg[ii.y], fabsf(vv.y));
            atomicAdd(&deg[ii.z], fabsf(vv.z));
            atomicAdd(&deg[ii.w], fabsf(vv.w));
        }
        if (gtid < (E & 3)) {
            int e = (E & ~3) + gtid;
            atomicAdd(&deg[ind[e]], fabsf(val[e]));
        }
    }

    // ---------------- P1c: stage layer-2 weights into LDS (overlay tile) ----
    float* w2s = smem;                 // [17][20] rows, 16B-aligned stride
    float* b1s = smem + L2DIM * 20;    // +340
    float* b2s = b1s + L1OUT;
    float* wcs = b2s + L2DIM;
    float* bcs = wcs + L2DIM;
    for (int idx = t; idx < L2DIM * L2DIM; idx += 256) {
        int c = idx / L2DIM, r = idx - c * L2DIM;
        w2s[c * 20 + r] = W2[idx];
    }
    if (t < L1OUT) b1s[t] = b1[t];
    if (t < L2DIM) b2s[t] = b2[t];
    if (t < L2DIM) wcs[t] = Wc[t];
    if (t == 0)    bcs[0] = bc[0];
    grid.sync();   // deg complete + weights staged (implies block barrier)

    // ---------------- P2: edge MLP + exp + segment-sum ----------------
    {
        int  e     = gtid;
        bool valid = e < E;
        int  i_c = 0, j_c = 0; float v_c = 0.f;
        if (valid) { i_c = ind[e]; j_c = ind[E + e]; v_c = val[e]; }

        while (valid) {
            // issue current gathers, then prefetch next indices (overlap)
            H16  a  = A[i_c];
            H16  bb = Bm[j_c];
            float dg = deg[i_c];

            int  e_n = e + GT;
            bool vn  = e_n < E;
            int  i_n = 0, j_n = 0; float v_n = 0.f;
            if (vn) { i_n = ind[e_n]; j_n = ind[E + e_n]; v_n = val[e_n]; }

            float x[L2DIM];
#pragma unroll
            for (int q = 0; q < 8; ++q) {
                float2 fa = __half22float2(a.h[q]);
                float2 fb = __half22float2(bb.h[q]);
                x[2 * q]     = lrelu(fa.x + fb.x + b1s[2 * q]);
                x[2 * q + 1] = lrelu(fa.y + fb.y + b1s[2 * q + 1]);
            }
            x[L1OUT] = fabsf(v_c) / dg;

            float acc[L2DIM];
#pragma unroll
            for (int r = 0; r < L2DIM; ++r) acc[r] = b2s[r];
#pragma unroll
            for (int c = 0; c < L2DIM; ++c) {
                float xc = x[c];
                const float4* r4 = reinterpret_cast<const float4*>(&w2s[c * 20]);
                float4 w0 = r4[0], w1v = r4[1], w2v = r4[2], w3 = r4[3];
                float  w16 = w2s[c * 20 + 16];
                acc[0]  += xc * w0.x;  acc[1]  += xc * w0.y;
                acc[2]  += xc * w0.z;  acc[3]  += xc * w0.w;
                acc[4]  += xc * w1v.x; acc[5]  += xc * w1v.y;
                acc[6]  += xc * w1v.z; acc[7]  += xc * w1v.w;
                acc[8]  += xc * w2v.x; acc[9]  += xc * w2v.y;
                acc[10] += xc * w2v.z; acc[11] += xc * w2v.w;
                acc[12] += xc * w3.x;  acc[13] += xc * w3.y;
                acc[14] += xc * w3.z;  acc[15] += xc * w3.w;
                acc[16] += xc * w16;
            }
            float ev = bcs[0];
#pragma unroll
            for (int r = 0; r < L2DIM; ++r) ev += lrelu(acc[r]) * wcs[r];

            float ex = __expf(ev);
            out[e] = ex;
            atomicAdd(&ssum[i_c], ex);

            e = e_n; i_c = i_n; j_c = j_n; v_c = v_n; valid = vn;
        }
    }
    grid.sync();

    // ---------------- P3: normalize (4 edges/thread) ----------------
    {
        const int E4 = E >> 2;
        for (int q = gtid; q < E4; q += GT) {
            int e = q << 2;
            int4   ii = *reinterpret_cast<const int4*>(ind + e);
            float4 vv = *reinterpret_cast<const float4*>(out + e);
            vv.x /= ssum[ii.x]; vv.y /= ssum[ii.y];
            vv.z /= ssum[ii.z]; vv.w /= ssum[ii.w];
            *reinterpret_cast<float4*>(out + e) = vv;
        }
        if (gtid < (E & 3)) {
            int e = (E & ~3) + gtid;
            out[e] = out[e] / ssum[ind[e]];
        }
    }
}

extern "C" void kernel_launch(void* const* d_in, const int* in_sizes, int n_in,
                              void* d_out, int out_size, void* d_ws, size_t ws_size,
                              hipStream_t stream) {
    const int*   Jt_ind = (const int*)  d_in[0];   // [2,E]
    const float* Jt_val = (const float*)d_in[1];   // [E]
    const float* f      = (const float*)d_in[2];   // [N,128]
    const float* W1 = (const float*)d_in[4];       // [256,16]
    const float* b1 = (const float*)d_in[5];       // [16]
    const float* W2 = (const float*)d_in[6];       // [17,17]
    const float* b2 = (const float*)d_in[7];       // [17]
    const float* Wc = (const float*)d_in[8];       // [17,1]
    const float* bc = (const float*)d_in[9];       // [1]

    int E = in_sizes[1];
    int N = in_sizes[2] / FDIM;
    float* out = (float*)d_out;                    // [E] fp32

    // workspace: A[N] H16 | B[N] H16 | deg[N] f32 | ssum[N] f32
    char* ws = (char*)d_ws;
    H16*   A    = (H16*)ws;    ws += (size_t)N * sizeof(H16);
    H16*   Bm   = (H16*)ws;    ws += (size_t)N * sizeof(H16);
    float* deg  = (float*)ws;  ws += (size_t)N * sizeof(float);
    float* ssum = (float*)ws;  ws += (size_t)N * sizeof(float);

    // cooperative grid = exactly full residency (capture-safe queries only)
    int dev = 0;
    hipGetDevice(&dev);
    int numCU = 256;
    hipDeviceGetAttribute(&numCU, hipDeviceAttributeMultiprocessorCount, dev);
    int blocksPerCU = 0;
    hipOccupancyMaxActiveBlocksPerMultiprocessor(&blocksPerCU, fused_gat, 256, 0);
    if (blocksPerCU < 1) blocksPerCU = 1;
    int grid = blocksPerCU * numCU;

    void* args[] = { (void*)&Jt_ind, (void*)&Jt_val, (void*)&f, (void*)&W1,
                     (void*)&b1, (void*)&W2, (void*)&b2, (void*)&Wc, (void*)&bc,
                     (void*)&out, (void*)&A, (void*)&Bm, (void*)&deg, (void*)&ssum,
                     (void*)&N, (void*)&E };
    hipLaunchCooperativeKernel(reinterpret_cast<void*>(fused_gat),
                               dim3(grid), dim3(256), args, 0, stream);
}

// Round 5
// 561.907 us; speedup vs baseline: 1.1054x; 1.1054x over previous
//
#include <hip/hip_runtime.h>
#include <hip/hip_fp16.h>
#include <math.h>

#define FDIM  128
#define L1OUT 16
#define L2DIM 17
#define TR    64      // f-rows per block in node_transform
#define TSTR  132     // tile row stride: 132*4B=528 (16B-aligned rows, 8-req/bank = LDS data floor)

// one 32-byte fp16 node row (16 halves); align 16 -> 2x global_load_dwordx4
struct __align__(16) H16 { __half2 h[8]; };

__device__ __forceinline__ float lrelu(float v) { return v >= 0.f ? v : 0.1f * v; }

// ============================================================================
// K1: A[n] = f[n] @ W1[0:128,:] + b1, B[n] = f[n] @ W1[128:256,:]  (fp16)
//     + degree atomics folded in (deg zeroed by memset before this kernel;
//       atomics are fire-and-forget, hidden behind the tile loop's memory)
// ============================================================================
__global__ __launch_bounds__(256, 4) void node_transform(
    const float* __restrict__ f, const float* __restrict__ W1,
    const float* __restrict__ b1,
    const int* __restrict__ ind_i, const float* __restrict__ val,
    H16* __restrict__ A, H16* __restrict__ B,
    float* __restrict__ deg, int N, int E)
{
    __shared__ __align__(16) float tile[TR * TSTR];   // 33.8 KB

    const int t    = threadIdx.x;
    const int gtid = blockIdx.x * 256 + t;
    const int GT   = gridDim.x * 256;

    // ---- degree atomics (4 edges/thread, grid-stride) ----
    {
        const int E4 = E >> 2;
        for (int q = gtid; q < E4; q += GT) {
            int e = q << 2;
            int4   ii = *reinterpret_cast<const int4*>(ind_i + e);
            float4 vv = *reinterpret_cast<const float4*>(val + e);
            atomicAdd(&deg[ii.x], fabsf(vv.x));
            atomicAdd(&deg[ii.y], fabsf(vv.y));
            atomicAdd(&deg[ii.z], fabsf(vv.z));
            atomicAdd(&deg[ii.w], fabsf(vv.w));
        }
        if (gtid < (E & 3)) {
            int e = (E & ~3) + gtid;
            atomicAdd(&deg[ind_i[e]], fabsf(val[e]));
        }
    }

    // ---- stage 64 f-rows coalesced into padded LDS tile ----
    const int base = blockIdx.x * TR;
#pragma unroll
    for (int q = 0; q < 8; ++q) {
        int i4 = t + 256 * q;              // float4 idx 0..2047
        int r  = i4 >> 5;                  // 32 float4 per row
        int c4 = i4 & 31;
        float4 v = make_float4(0.f, 0.f, 0.f, 0.f);
        if (base + r < N)
            v = reinterpret_cast<const float4*>(f + (size_t)(base + r) * FDIM)[c4];
        *reinterpret_cast<float4*>(&tile[r * TSTR + c4 * 4]) = v;
    }
    __syncthreads();

    // ---- compute: wave w -> 8 cols of A or B; lane -> row ----
    const int lane    = t & 63;
    const int w       = t >> 6;                  // 0..3
    const int colbase = (w & 1) * 8;             // cols 0-7 / 8-15
    const int isB     = w >> 1;                  // 0: A (W1 rows 0-127), 1: B (128-255)
    const float* wbase = W1 + (size_t)(isB * FDIM) * L1OUT + colbase;

    float acc[8];
#pragma unroll
    for (int c = 0; c < 8; ++c) acc[c] = isB ? 0.f : b1[colbase + c];  // fold b1 into A

    const float* trow = &tile[lane * TSTR];
#pragma unroll 2
    for (int k4 = 0; k4 < FDIM / 4; ++k4) {
        float4 xv = *reinterpret_cast<const float4*>(trow + k4 * 4);  // ds_read_b128
#pragma unroll
        for (int u = 0; u < 4; ++u) {
            float x = (u == 0) ? xv.x : (u == 1) ? xv.y : (u == 2) ? xv.z : xv.w;
            const float* wr = wbase + (size_t)(k4 * 4 + u) * L1OUT;
            float4 w0  = *reinterpret_cast<const float4*>(wr);        // uniform, L1-hit
            float4 w1v = *reinterpret_cast<const float4*>(wr + 4);
            acc[0] += x * w0.x;  acc[1] += x * w0.y;
            acc[2] += x * w0.z;  acc[3] += x * w0.w;
            acc[4] += x * w1v.x; acc[5] += x * w1v.y;
            acc[6] += x * w1v.z; acc[7] += x * w1v.w;
        }
    }

    int n = base + lane;
    if (n < N) {
        __align__(16) __half2 h[4];
#pragma unroll
        for (int q = 0; q < 4; ++q)
            h[q] = __floats2half2_rn(acc[2 * q], acc[2 * q + 1]);
        H16* arr = isB ? B : A;
        float4* dst = reinterpret_cast<float4*>(
            reinterpret_cast<char*>(arr + n) + (w & 1) * 16);
        *dst = *reinterpret_cast<float4*>(h);
    }
}

// ============================================================================
// K2: per-edge MLP -> exp -> segment-sum. 2 contiguous edges/thread for
// gather MLP (4 row-gathers + 2 deg-gathers in flight). Weights in LDS
// (stride-20 rows, 16B-aligned broadcast reads). b1 pre-folded into A.
// Softmax max-pass removed: identical ratios; |e_val| <~ 15 (fp32-safe).
// ============================================================================
__global__ __launch_bounds__(256, 4) void edge_mlp(
    const int* __restrict__ ind, const float* __restrict__ val,
    const H16* __restrict__ A, const H16* __restrict__ B,
    const float* __restrict__ deg,
    const float* __restrict__ W2, const float* __restrict__ b2,
    const float* __restrict__ Wc, const float* __restrict__ bc,
    float* __restrict__ eout, float* __restrict__ ssum, int E)
{
    __shared__ float w2s[L2DIM * 20];   // row c at w2s[c*20], 16B-aligned
    __shared__ float b2s[L2DIM];
    __shared__ float wcs[L2DIM];
    __shared__ float bc0s;

    const int t = threadIdx.x;
    for (int idx = t; idx < L2DIM * L2DIM; idx += 256) {
        int c = idx / L2DIM, r = idx - c * L2DIM;
        w2s[c * 20 + r] = W2[idx];
    }
    if (t < L2DIM) b2s[t] = b2[t];
    if (t < L2DIM) wcs[t] = Wc[t];
    if (t == 0)    bc0s   = bc[0];
    __syncthreads();

    const int e0 = (blockIdx.x * 256 + t) * 2;
    if (e0 >= E) return;
    const bool has1 = (e0 + 1) < E;

    // ---- issue every independent load up front ----
    int2 ii = *reinterpret_cast<const int2*>(ind + e0);      // i0,i1 (e0 even -> 8B aligned)
    int  j0 = ind[E + e0];
    int  j1 = has1 ? ind[E + e0 + 1] : j0;
    float2 vv = *reinterpret_cast<const float2*>(val + e0);
    int i0 = ii.x, i1 = has1 ? ii.y : ii.x;

    H16 a0 = A[i0], bb0 = B[j0];
    H16 a1 = A[i1], bb1 = B[j1];
    float dg0 = deg[i0];
    float dg1 = deg[i1];

    float ex[2];
#pragma unroll
    for (int s = 0; s < 2; ++s) {
        const H16& a  = s ? a1 : a0;
        const H16& bb = s ? bb1 : bb0;
        float nv = fabsf(s ? vv.y : vv.x) / (s ? dg1 : dg0);

        float x[L2DIM];
#pragma unroll
        for (int q = 0; q < 8; ++q) {
            float2 fa = __half22float2(a.h[q]);
            float2 fb = __half22float2(bb.h[q]);
            x[2 * q]     = lrelu(fa.x + fb.x);      // b1 already folded into A
            x[2 * q + 1] = lrelu(fa.y + fb.y);
        }
        x[L1OUT] = nv;

        float acc[L2DIM];
#pragma unroll
        for (int r = 0; r < L2DIM; ++r) acc[r] = b2s[r];
#pragma unroll
        for (int c = 0; c < L2DIM; ++c) {
            float xc = x[c];
            const float4* r4 = reinterpret_cast<const float4*>(&w2s[c * 20]);
            float4 w0 = r4[0], w1v = r4[1], w2v = r4[2], w3 = r4[3];
            float  w16 = w2s[c * 20 + 16];
            acc[0]  += xc * w0.x;  acc[1]  += xc * w0.y;
            acc[2]  += xc * w0.z;  acc[3]  += xc * w0.w;
            acc[4]  += xc * w1v.x; acc[5]  += xc * w1v.y;
            acc[6]  += xc * w1v.z; acc[7]  += xc * w1v.w;
            acc[8]  += xc * w2v.x; acc[9]  += xc * w2v.y;
            acc[10] += xc * w2v.z; acc[11] += xc * w2v.w;
            acc[12] += xc * w3.x;  acc[13] += xc * w3.y;
            acc[14] += xc * w3.z;  acc[15] += xc * w3.w;
            acc[16] += xc * w16;
        }
        float ev = bc0s;
#pragma unroll
        for (int r = 0; r < L2DIM; ++r) ev += lrelu(acc[r]) * wcs[r];
        ex[s] = __expf(ev);
    }

    atomicAdd(&ssum[i0], ex[0]);
    if (has1) {
        atomicAdd(&ssum[i1], ex[1]);
        *reinterpret_cast<float2*>(eout + e0) = make_float2(ex[0], ex[1]);
    } else {
        eout[e0] = ex[0];
    }
}

// ============================================================================
// K3: out = ex / s[i], 4 edges/thread vectorized
// ============================================================================
__global__ void normalize(const int* __restrict__ ind_i, const float* __restrict__ ssum,
                          float* __restrict__ ex, int E) {
    int t = blockIdx.x * blockDim.x + threadIdx.x;
    int e = t * 4;
    if (e + 3 < E) {
        int4   ii = *reinterpret_cast<const int4*>(ind_i + e);
        float4 vv = *reinterpret_cast<const float4*>(ex + e);
        vv.x /= ssum[ii.x];
        vv.y /= ssum[ii.y];
        vv.z /= ssum[ii.z];
        vv.w /= ssum[ii.w];
        *reinterpret_cast<float4*>(ex + e) = vv;
    } else {
        for (; e < E; ++e) ex[e] = ex[e] / ssum[ind_i[e]];
    }
}

extern "C" void kernel_launch(void* const* d_in, const int* in_sizes, int n_in,
                              void* d_out, int out_size, void* d_ws, size_t ws_size,
                              hipStream_t stream) {
    const int*   Jt_ind = (const int*)  d_in[0];   // [2,E]
    const float* Jt_val = (const float*)d_in[1];   // [E]
    const float* f      = (const float*)d_in[2];   // [N,128]
    const float* W1 = (const float*)d_in[4];       // [256,16]
    const float* b1 = (const float*)d_in[5];       // [16]
    const float* W2 = (const float*)d_in[6];       // [17,17]
    const float* b2 = (const float*)d_in[7];       // [17]
    const float* Wc = (const float*)d_in[8];       // [17,1]
    const float* bc = (const float*)d_in[9];       // [1]

    const int E = in_sizes[1];
    const int N = in_sizes[2] / FDIM;
    float* out = (float*)d_out;                    // [E] fp32

    // workspace: deg[N] f32 | ssum[N] f32 (contiguous, one memset) | A[N] | B[N]
    char* ws = (char*)d_ws;
    float* deg  = (float*)ws;  ws += (size_t)N * sizeof(float);
    float* ssum = (float*)ws;  ws += (size_t)N * sizeof(float);
    H16*   A    = (H16*)ws;    ws += (size_t)N * sizeof(H16);
    H16*   Bm   = (H16*)ws;    ws += (size_t)N * sizeof(H16);

    const int B256 = 256;
    const int nblk = (N + TR - 1) / TR;                     // node tiles
    const int eblk = ((E + 1) / 2 + B256 - 1) / B256;       // 2 edges/thread
    const int qblk = ((E + 3) / 4 + B256 - 1) / B256;       // 4 edges/thread

    hipMemsetAsync(deg, 0, 2 * (size_t)N * sizeof(float), stream);
    node_transform<<<nblk, B256, 0, stream>>>(f, W1, b1, Jt_ind, Jt_val,
                                              A, Bm, deg, N, E);
    edge_mlp      <<<eblk, B256, 0, stream>>>(Jt_ind, Jt_val, A, Bm, deg,
                                              W2, b2, Wc, bc, out, ssum, E);
    normalize     <<<qblk, B256, 0, stream>>>(Jt_ind, ssum, out, E);
}

// Round 6
// 546.475 us; speedup vs baseline: 1.1366x; 1.0282x over previous
//
#include <hip/hip_runtime.h>
#include <hip/hip_fp16.h>
#include <math.h>

#define FDIM  128
#define L1OUT 16
#define L2DIM 17
#define TR    64      // f-rows per block in node_transform
#define TSTR  132     // tile row stride: 528 B (16B-aligned rows)

// one 32-byte fp16 node row (16 halves); align 16 -> 2x global_load_dwordx4
struct __align__(16) H16 { __half2 h[8]; };

__device__ __forceinline__ float lrelu(float v) { return v >= 0.f ? v : 0.1f * v; }

// ============================================================================
// K1: A[n] = f[n] @ W1[0:128,:] + b1, B[n] = f[n] @ W1[128:256,:]  (fp16)
//     + degree atomics folded in (deg zeroed by memsetAsync before this)
// ============================================================================
__global__ void node_transform(
    const float* __restrict__ f, const float* __restrict__ W1,
    const float* __restrict__ b1,
    const int* __restrict__ ind_i, const float* __restrict__ val,
    H16* __restrict__ A, H16* __restrict__ B,
    float* __restrict__ deg, int N, int E)
{
    __shared__ __align__(16) float tile[TR * TSTR];   // 33.8 KB

    const int t    = threadIdx.x;
    const int gtid = blockIdx.x * 256 + t;
    const int GT   = gridDim.x * 256;

    // ---- degree atomics (4 edges/thread, grid-stride, fire-and-forget) ----
    {
        const int E4 = E >> 2;
        for (int q = gtid; q < E4; q += GT) {
            int e = q << 2;
            int4   ii = *reinterpret_cast<const int4*>(ind_i + e);
            float4 vv = *reinterpret_cast<const float4*>(val + e);
            atomicAdd(&deg[ii.x], fabsf(vv.x));
            atomicAdd(&deg[ii.y], fabsf(vv.y));
            atomicAdd(&deg[ii.z], fabsf(vv.z));
            atomicAdd(&deg[ii.w], fabsf(vv.w));
        }
        if (gtid < (E & 3)) {
            int e = (E & ~3) + gtid;
            atomicAdd(&deg[ind_i[e]], fabsf(val[e]));
        }
    }

    // ---- stage 64 f-rows coalesced into padded LDS tile ----
    const int base = blockIdx.x * TR;
#pragma unroll
    for (int q = 0; q < 8; ++q) {
        int i4 = t + 256 * q;              // float4 idx 0..2047
        int r  = i4 >> 5;                  // 32 float4 per row
        int c4 = i4 & 31;
        float4 v = make_float4(0.f, 0.f, 0.f, 0.f);
        if (base + r < N)
            v = reinterpret_cast<const float4*>(f + (size_t)(base + r) * FDIM)[c4];
        *reinterpret_cast<float4*>(&tile[r * TSTR + c4 * 4]) = v;
    }
    __syncthreads();

    // ---- compute: wave w -> 8 cols of A or B; lane -> row ----
    const int lane    = t & 63;
    const int w       = t >> 6;                  // 0..3
    const int colbase = (w & 1) * 8;             // cols 0-7 / 8-15
    const int isB     = w >> 1;                  // 0: A (W1 rows 0-127), 1: B
    const float* wbase = W1 + (size_t)(isB * FDIM) * L1OUT + colbase;

    float acc[8];
#pragma unroll
    for (int c = 0; c < 8; ++c) acc[c] = isB ? 0.f : b1[colbase + c];  // fold b1

    const float* trow = &tile[lane * TSTR];
#pragma unroll 2
    for (int k4 = 0; k4 < FDIM / 4; ++k4) {
        float4 xv = *reinterpret_cast<const float4*>(trow + k4 * 4);  // ds_read_b128
#pragma unroll
        for (int u = 0; u < 4; ++u) {
            float x = (u == 0) ? xv.x : (u == 1) ? xv.y : (u == 2) ? xv.z : xv.w;
            const float* wr = wbase + (size_t)(k4 * 4 + u) * L1OUT;
            float4 w0  = *reinterpret_cast<const float4*>(wr);        // uniform, L1-hit
            float4 w1v = *reinterpret_cast<const float4*>(wr + 4);
            acc[0] += x * w0.x;  acc[1] += x * w0.y;
            acc[2] += x * w0.z;  acc[3] += x * w0.w;
            acc[4] += x * w1v.x; acc[5] += x * w1v.y;
            acc[6] += x * w1v.z; acc[7] += x * w1v.w;
        }
    }

    int n = base + lane;
    if (n < N) {
        __align__(16) __half2 h[4];
#pragma unroll
        for (int q = 0; q < 4; ++q)
            h[q] = __floats2half2_rn(acc[2 * q], acc[2 * q + 1]);
        H16* arr = isB ? B : A;                  // global-pointer select: safe
        float4* dst = reinterpret_cast<float4*>(
            reinterpret_cast<char*>(arr + n) + (w & 1) * 16);
        *dst = *reinterpret_cast<float4*>(h);
    }
}

// ============================================================================
// Per-edge MLP body. R2-proven-clean codegen pattern: __forceinline__ with
// const-ref H16 params, called twice sequentially. NO ternary selection of
// local addresses anywhere (that caused R5's 664 MB scratch-spill disaster).
// ============================================================================
__device__ __forceinline__ float edge_val(const H16& a, const H16& bb, float nv,
                                          const float* __restrict__ w2s,
                                          const float* __restrict__ b2s,
                                          const float* __restrict__ wcs,
                                          float bc0) {
    float x[L2DIM];
#pragma unroll
    for (int q = 0; q < 8; ++q) {
        float2 fa = __half22float2(a.h[q]);
        float2 fb = __half22float2(bb.h[q]);
        x[2 * q]     = lrelu(fa.x + fb.x);       // b1 pre-folded into A
        x[2 * q + 1] = lrelu(fa.y + fb.y);
    }
    x[L1OUT] = nv;

    float acc[L2DIM];
#pragma unroll
    for (int r = 0; r < L2DIM; ++r) acc[r] = b2s[r];
#pragma unroll
    for (int c = 0; c < L2DIM; ++c) {
        float xc = x[c];
        const float4* r4 = reinterpret_cast<const float4*>(&w2s[c * 20]);
        float4 w0 = r4[0], w1v = r4[1], w2v = r4[2], w3 = r4[3];
        float  w16 = w2s[c * 20 + 16];
        acc[0]  += xc * w0.x;  acc[1]  += xc * w0.y;
        acc[2]  += xc * w0.z;  acc[3]  += xc * w0.w;
        acc[4]  += xc * w1v.x; acc[5]  += xc * w1v.y;
        acc[6]  += xc * w1v.z; acc[7]  += xc * w1v.w;
        acc[8]  += xc * w2v.x; acc[9]  += xc * w2v.y;
        acc[10] += xc * w2v.z; acc[11] += xc * w2v.w;
        acc[12] += xc * w3.x;  acc[13] += xc * w3.y;
        acc[14] += xc * w3.z;  acc[15] += xc * w3.w;
        acc[16] += xc * w16;
    }
    float ev = bc0;
#pragma unroll
    for (int r = 0; r < L2DIM; ++r) ev += lrelu(acc[r]) * wcs[r];
    return ev;
}

// ============================================================================
// K2: per-edge MLP -> exp -> segment-sum. 2 contiguous edges/thread
// (4 H16 row-gathers + 2 deg-gathers in flight). Weights in LDS.
// Softmax max-pass removed: identical ratios; |e_val| <~ 15 (fp32-safe).
// ============================================================================
__global__ void edge_mlp(
    const int* __restrict__ ind, const float* __restrict__ val,
    const H16* __restrict__ A, const H16* __restrict__ B,
    const float* __restrict__ deg,
    const float* __restrict__ W2, const float* __restrict__ b2,
    const float* __restrict__ Wc, const float* __restrict__ bc,
    float* __restrict__ eout, float* __restrict__ ssum, int E)
{
    __shared__ float w2s[L2DIM * 20];   // row c at w2s[c*20], 16B-aligned
    __shared__ float b2s[L2DIM];
    __shared__ float wcs[L2DIM];
    __shared__ float bc0s;

    const int t = threadIdx.x;
    for (int idx = t; idx < L2DIM * L2DIM; idx += 256) {
        int c = idx / L2DIM, r = idx - c * L2DIM;
        w2s[c * 20 + r] = W2[idx];
    }
    if (t < L2DIM) b2s[t] = b2[t];
    if (t < L2DIM) wcs[t] = Wc[t];
    if (t == 0)    bc0s   = bc[0];
    __syncthreads();

    const int e0 = (blockIdx.x * 256 + t) * 2;
    if (e0 >= E) return;
    const bool has1 = (e0 + 1) < E;

    // ---- issue all independent loads up front ----
    int2   ii = *reinterpret_cast<const int2*>(ind + e0);     // dests i0,i1
    int    j0 = ind[E + e0];
    int    j1 = has1 ? ind[E + e0 + 1] : j0;
    float2 vv = *reinterpret_cast<const float2*>(val + e0);
    int i0 = ii.x;
    int i1 = has1 ? ii.y : ii.x;

    H16 a0  = A[i0];
    H16 bb0 = B[j0];
    H16 a1  = A[i1];
    H16 bb1 = B[j1];
    float dg0 = deg[i0];
    float dg1 = deg[i1];

    float bc0 = bc0s;
    float ev0 = edge_val(a0, bb0, fabsf(vv.x) / dg0, w2s, b2s, wcs, bc0);
    float ex0 = __expf(ev0);
    float ev1 = edge_val(a1, bb1, fabsf(vv.y) / dg1, w2s, b2s, wcs, bc0);
    float ex1 = __expf(ev1);

    atomicAdd(&ssum[i0], ex0);
    if (has1) {
        atomicAdd(&ssum[i1], ex1);
        *reinterpret_cast<float2*>(eout + e0) = make_float2(ex0, ex1);
    } else {
        eout[e0] = ex0;
    }
}

// ============================================================================
// K3: out = ex / s[i], 4 edges/thread vectorized
// ============================================================================
__global__ void normalize(const int* __restrict__ ind_i, const float* __restrict__ ssum,
                          float* __restrict__ ex, int E) {
    int t = blockIdx.x * blockDim.x + threadIdx.x;
    int e = t * 4;
    if (e + 3 < E) {
        int4   ii = *reinterpret_cast<const int4*>(ind_i + e);
        float4 vv = *reinterpret_cast<const float4*>(ex + e);
        vv.x /= ssum[ii.x];
        vv.y /= ssum[ii.y];
        vv.z /= ssum[ii.z];
        vv.w /= ssum[ii.w];
        *reinterpret_cast<float4*>(ex + e) = vv;
    } else {
        for (; e < E; ++e) ex[e] = ex[e] / ssum[ind_i[e]];
    }
}

extern "C" void kernel_launch(void* const* d_in, const int* in_sizes, int n_in,
                              void* d_out, int out_size, void* d_ws, size_t ws_size,
                              hipStream_t stream) {
    const int*   Jt_ind = (const int*)  d_in[0];   // [2,E]
    const float* Jt_val = (const float*)d_in[1];   // [E]
    const float* f      = (const float*)d_in[2];   // [N,128]
    const float* W1 = (const float*)d_in[4];       // [256,16]
    const float* b1 = (const float*)d_in[5];       // [16]
    const float* W2 = (const float*)d_in[6];       // [17,17]
    const float* b2 = (const float*)d_in[7];       // [17]
    const float* Wc = (const float*)d_in[8];       // [17,1]
    const float* bc = (const float*)d_in[9];       // [1]

    const int E = in_sizes[1];
    const int N = in_sizes[2] / FDIM;
    float* out = (float*)d_out;                    // [E] fp32

    // workspace: deg[N] | ssum[N] (contiguous -> one memset) | A[N] | B[N]
    char* ws = (char*)d_ws;
    float* deg  = (float*)ws;  ws += (size_t)N * sizeof(float);
    float* ssum = (float*)ws;  ws += (size_t)N * sizeof(float);
    H16*   A    = (H16*)ws;    ws += (size_t)N * sizeof(H16);
    H16*   Bm   = (H16*)ws;    ws += (size_t)N * sizeof(H16);

    const int B256 = 256;
    const int nblk = (N + TR - 1) / TR;                     // node tiles
    const int eblk = ((E + 1) / 2 + B256 - 1) / B256;       // 2 edges/thread
    const int qblk = ((E + 3) / 4 + B256 - 1) / B256;       // 4 edges/thread

    hipMemsetAsync(deg, 0, 2 * (size_t)N * sizeof(float), stream);
    node_transform<<<nblk, B256, 0, stream>>>(f, W1, b1, Jt_ind, Jt_val,
                                              A, Bm, deg, N, E);
    edge_mlp      <<<eblk, B256, 0, stream>>>(Jt_ind, Jt_val, A, Bm, deg,
                                              W2, b2, Wc, bc, out, ssum, E);
    normalize     <<<qblk, B256, 0, stream>>>(Jt_ind, ssum, out, E);
}

// Round 7
// 255.339 us; speedup vs baseline: 2.4326x; 2.1402x over previous
//
#include <hip/hip_runtime.h>
#include <hip/hip_fp16.h>
#include <math.h>

#define FDIM  128
#define L1OUT 16
#define L2DIM 17
#define TR    64      // f-rows per block in node_transform
#define TSTR  132     // tile row stride: 528 B (16B-aligned rows)

// one 32-byte fp16 node row (16 halves); align 16 -> 2x global_load_dwordx4
struct __align__(16) H16 { __half2 h[8]; };

__device__ __forceinline__ float lrelu(float v) { return v >= 0.f ? v : 0.1f * v; }

// ============================================================================
// K1: A[n] = f[n] @ W1[0:128,:] + b1, B[n] = f[n] @ W1[128:256,:]  (fp16)
//     + degree atomics folded in (deg zeroed by memsetAsync before this)
// ============================================================================
__global__ void node_transform(
    const float* __restrict__ f, const float* __restrict__ W1,
    const float* __restrict__ b1,
    const int* __restrict__ ind_i, const float* __restrict__ val,
    H16* __restrict__ A, H16* __restrict__ B,
    float* __restrict__ deg, int N, int E)
{
    __shared__ __align__(16) float tile[TR * TSTR];   // 33.8 KB

    const int t    = threadIdx.x;
    const int gtid = blockIdx.x * 256 + t;
    const int GT   = gridDim.x * 256;

    // ---- degree atomics (4 edges/thread, grid-stride, fire-and-forget) ----
    {
        const int E4 = E >> 2;
        for (int q = gtid; q < E4; q += GT) {
            int e = q << 2;
            int4   ii = *reinterpret_cast<const int4*>(ind_i + e);
            float4 vv = *reinterpret_cast<const float4*>(val + e);
            atomicAdd(&deg[ii.x], fabsf(vv.x));
            atomicAdd(&deg[ii.y], fabsf(vv.y));
            atomicAdd(&deg[ii.z], fabsf(vv.z));
            atomicAdd(&deg[ii.w], fabsf(vv.w));
        }
        if (gtid < (E & 3)) {
            int e = (E & ~3) + gtid;
            atomicAdd(&deg[ind_i[e]], fabsf(val[e]));
        }
    }

    // ---- stage 64 f-rows coalesced into padded LDS tile ----
    const int base = blockIdx.x * TR;
#pragma unroll
    for (int q = 0; q < 8; ++q) {
        int i4 = t + 256 * q;              // float4 idx 0..2047
        int r  = i4 >> 5;                  // 32 float4 per row
        int c4 = i4 & 31;
        float4 v = make_float4(0.f, 0.f, 0.f, 0.f);
        if (base + r < N)
            v = reinterpret_cast<const float4*>(f + (size_t)(base + r) * FDIM)[c4];
        *reinterpret_cast<float4*>(&tile[r * TSTR + c4 * 4]) = v;
    }
    __syncthreads();

    // ---- compute: wave w -> 8 cols of A or B; lane -> row ----
    const int lane    = t & 63;
    const int w       = t >> 6;                  // 0..3
    const int colbase = (w & 1) * 8;             // cols 0-7 / 8-15
    const int isB     = w >> 1;                  // 0: A (W1 rows 0-127), 1: B
    const float* wbase = W1 + (size_t)(isB * FDIM) * L1OUT + colbase;

    float acc[8];
#pragma unroll
    for (int c = 0; c < 8; ++c) acc[c] = isB ? 0.f : b1[colbase + c];  // fold b1

    const float* trow = &tile[lane * TSTR];
#pragma unroll 2
    for (int k4 = 0; k4 < FDIM / 4; ++k4) {
        float4 xv = *reinterpret_cast<const float4*>(trow + k4 * 4);  // ds_read_b128
#pragma unroll
        for (int u = 0; u < 4; ++u) {
            float x = (u == 0) ? xv.x : (u == 1) ? xv.y : (u == 2) ? xv.z : xv.w;
            const float* wr = wbase + (size_t)(k4 * 4 + u) * L1OUT;
            float4 w0  = *reinterpret_cast<const float4*>(wr);        // uniform, L1-hit
            float4 w1v = *reinterpret_cast<const float4*>(wr + 4);
            acc[0] += x * w0.x;  acc[1] += x * w0.y;
            acc[2] += x * w0.z;  acc[3] += x * w0.w;
            acc[4] += x * w1v.x; acc[5] += x * w1v.y;
            acc[6] += x * w1v.z; acc[7] += x * w1v.w;
        }
    }

    int n = base + lane;
    if (n < N) {
        __align__(16) __half2 h[4];
#pragma unroll
        for (int q = 0; q < 4; ++q)
            h[q] = __floats2half2_rn(acc[2 * q], acc[2 * q + 1]);
        H16* arr = isB ? B : A;                  // global-pointer select: safe
        float4* dst = reinterpret_cast<float4*>(
            reinterpret_cast<char*>(arr + n) + (w & 1) * 16);
        *dst = *reinterpret_cast<float4*>(h);
    }
}

// ============================================================================
// K2: per-edge MLP -> exp -> segment-sum. ONE edge per thread — the R3-measured
// clean configuration (64 VGPR, no scratch). 2-edge/thread with LDS weights
// spills ~1.6KB/thread (R5/R6: 658 MB scratch WRITE) — do not revisit without
// SGPR-resident weights. Weights in LDS (stride-20 rows, 16B-aligned).
// Softmax max-pass removed: identical ratios; |e_val| <~ 15 (fp32-safe).
// ============================================================================
__global__ void edge_mlp(
    const int* __restrict__ ind, const float* __restrict__ val,
    const H16* __restrict__ A, const H16* __restrict__ B,
    const float* __restrict__ deg,
    const float* __restrict__ W2, const float* __restrict__ b2,
    const float* __restrict__ Wc, const float* __restrict__ bc,
    float* __restrict__ eout, float* __restrict__ ssum, int E)
{
    __shared__ float w2s[L2DIM * 20];   // row c at w2s[c*20], 16B-aligned
    __shared__ float b2s[L2DIM];
    __shared__ float wcs[L2DIM];
    __shared__ float bc0s;

    const int t = threadIdx.x;
    for (int idx = t; idx < L2DIM * L2DIM; idx += 512) {
        int c = idx / L2DIM, r = idx - c * L2DIM;
        w2s[c * 20 + r] = W2[idx];
    }
    if (t < L2DIM) b2s[t] = b2[t];
    if (t < L2DIM) wcs[t] = Wc[t];
    if (t == 0)    bc0s   = bc[0];
    __syncthreads();

    const int e = blockIdx.x * 512 + t;
    if (e >= E) return;

    int   i = ind[e];
    int   j = ind[E + e];
    H16   a  = A[i];                     // 2x global_load_dwordx4 gather
    H16   bb = B[j];
    float v  = val[e];
    float dg = deg[i];

    float x[L2DIM];
#pragma unroll
    for (int q = 0; q < 8; ++q) {
        float2 fa = __half22float2(a.h[q]);
        float2 fb = __half22float2(bb.h[q]);
        x[2 * q]     = lrelu(fa.x + fb.x);       // b1 pre-folded into A
        x[2 * q + 1] = lrelu(fa.y + fb.y);
    }
    x[L1OUT] = fabsf(v) / dg;

    float acc[L2DIM];
#pragma unroll
    for (int r = 0; r < L2DIM; ++r) acc[r] = b2s[r];
#pragma unroll
    for (int c = 0; c < L2DIM; ++c) {
        float xc = x[c];
        const float4* r4 = reinterpret_cast<const float4*>(&w2s[c * 20]);
        float4 w0 = r4[0], w1v = r4[1], w2v = r4[2], w3 = r4[3];
        float  w16 = w2s[c * 20 + 16];
        acc[0]  += xc * w0.x;  acc[1]  += xc * w0.y;
        acc[2]  += xc * w0.z;  acc[3]  += xc * w0.w;
        acc[4]  += xc * w1v.x; acc[5]  += xc * w1v.y;
        acc[6]  += xc * w1v.z; acc[7]  += xc * w1v.w;
        acc[8]  += xc * w2v.x; acc[9]  += xc * w2v.y;
        acc[10] += xc * w2v.z; acc[11] += xc * w2v.w;
        acc[12] += xc * w3.x;  acc[13] += xc * w3.y;
        acc[14] += xc * w3.z;  acc[15] += xc * w3.w;
        acc[16] += xc * w16;
    }
    float ev = bc0s;
#pragma unroll
    for (int r = 0; r < L2DIM; ++r) ev += lrelu(acc[r]) * wcs[r];

    float ex = __expf(ev);
    eout[e] = ex;
    atomicAdd(&ssum[i], ex);
}

// ============================================================================
// K3: out = ex / s[i], 4 edges/thread vectorized
// ============================================================================
__global__ void normalize(const int* __restrict__ ind_i, const float* __restrict__ ssum,
                          float* __restrict__ ex, int E) {
    int t = blockIdx.x * blockDim.x + threadIdx.x;
    int e = t * 4;
    if (e + 3 < E) {
        int4   ii = *reinterpret_cast<const int4*>(ind_i + e);
        float4 vv = *reinterpret_cast<const float4*>(ex + e);
        vv.x /= ssum[ii.x];
        vv.y /= ssum[ii.y];
        vv.z /= ssum[ii.z];
        vv.w /= ssum[ii.w];
        *reinterpret_cast<float4*>(ex + e) = vv;
    } else {
        for (; e < E; ++e) ex[e] = ex[e] / ssum[ind_i[e]];
    }
}

extern "C" void kernel_launch(void* const* d_in, const int* in_sizes, int n_in,
                              void* d_out, int out_size, void* d_ws, size_t ws_size,
                              hipStream_t stream) {
    const int*   Jt_ind = (const int*)  d_in[0];   // [2,E]
    const float* Jt_val = (const float*)d_in[1];   // [E]
    const float* f      = (const float*)d_in[2];   // [N,128]
    const float* W1 = (const float*)d_in[4];       // [256,16]
    const float* b1 = (const float*)d_in[5];       // [16]
    const float* W2 = (const float*)d_in[6];       // [17,17]
    const float* b2 = (const float*)d_in[7];       // [17]
    const float* Wc = (const float*)d_in[8];       // [17,1]
    const float* bc = (const float*)d_in[9];       // [1]

    const int E = in_sizes[1];
    const int N = in_sizes[2] / FDIM;
    float* out = (float*)d_out;                    // [E] fp32

    // workspace: deg[N] | ssum[N] (contiguous -> one memset) | A[N] | B[N]
    char* ws = (char*)d_ws;
    float* deg  = (float*)ws;  ws += (size_t)N * sizeof(float);
    float* ssum = (float*)ws;  ws += (size_t)N * sizeof(float);
    H16*   A    = (H16*)ws;    ws += (size_t)N * sizeof(H16);
    H16*   Bm   = (H16*)ws;    ws += (size_t)N * sizeof(H16);

    const int B256 = 256;
    const int B512 = 512;
    const int nblk = (N + TR - 1) / TR;                     // node tiles
    const int eblk = (E + B512 - 1) / B512;                 // 1 edge/thread
    const int qblk = ((E + 3) / 4 + B256 - 1) / B256;       // 4 edges/thread

    hipMemsetAsync(deg, 0, 2 * (size_t)N * sizeof(float), stream);
    node_transform<<<nblk, B256, 0, stream>>>(f, W1, b1, Jt_ind, Jt_val,
                                              A, Bm, deg, N, E);
    edge_mlp      <<<eblk, B512, 0, stream>>>(Jt_ind, Jt_val, A, Bm, deg,
                                              W2, b2, Wc, bc, out, ssum, E);
    normalize     <<<qblk, B256, 0, stream>>>(Jt_ind, ssum, out, E);
}

// Round 8
// 223.064 us; speedup vs baseline: 2.7846x; 1.1447x over previous
//
#include <hip/hip_runtime.h>
#include <hip/hip_fp16.h>
#include <math.h>

#define FDIM  128
#define L1OUT 16
#define L2DIM 17
#define TR    64      // f-rows per block in node_transform
#define TSTR  132     // tile row stride: 528 B (16B-aligned rows, measured 0 bank conflicts)

// one 32-byte fp16 node row (16 halves); align 16 -> 2x global_load_dwordx4
struct __align__(16) H16 { __half2 h[8]; };

__device__ __forceinline__ float lrelu(float v) { return v >= 0.f ? v : 0.1f * v; }

// ============================================================================
// K1: A[n] = f[n] @ W1[0:128,:] + b1, B[n] = f[n] @ W1[128:256,:]  (fp16)
//     + degree atomics folded in (deg zeroed by memsetAsync before this)
// R7 lesson: W1 read per-k from GLOBAL is the stall — wave-uniform vector
// loads grind the TA (~16 cyc each, 256/thread -> ~40+ us). W1 now staged to
// LDS once; uniform ds_read_b128 broadcasts are near-free. LDS 49 KB -> 3
// blocks/CU (unchanged vs measured 37% occupancy).
// ============================================================================
__global__ void node_transform(
    const float* __restrict__ f, const float* __restrict__ W1,
    const float* __restrict__ b1,
    const int* __restrict__ ind_i, const float* __restrict__ val,
    H16* __restrict__ A, H16* __restrict__ B,
    float* __restrict__ deg, int N, int E)
{
    __shared__ __align__(16) float tile[TR * TSTR];   // 33.8 KB
    __shared__ __align__(16) float w1s[2 * FDIM * L1OUT];  // 16 KB

    const int t    = threadIdx.x;
    const int gtid = blockIdx.x * 256 + t;
    const int GT   = gridDim.x * 256;

    // ---- degree atomics (4 edges/thread, grid-stride, fire-and-forget) ----
    {
        const int E4 = E >> 2;
        for (int q = gtid; q < E4; q += GT) {
            int e = q << 2;
            int4   ii = *reinterpret_cast<const int4*>(ind_i + e);
            float4 vv = *reinterpret_cast<const float4*>(val + e);
            atomicAdd(&deg[ii.x], fabsf(vv.x));
            atomicAdd(&deg[ii.y], fabsf(vv.y));
            atomicAdd(&deg[ii.z], fabsf(vv.z));
            atomicAdd(&deg[ii.w], fabsf(vv.w));
        }
        if (gtid < (E & 3)) {
            int e = (E & ~3) + gtid;
            atomicAdd(&deg[ind_i[e]], fabsf(val[e]));
        }
    }

    // ---- stage W1 into LDS: 4096 floats = 1024 float4, coalesced ----
    {
        const float4* src = reinterpret_cast<const float4*>(W1);
        float4*       dst = reinterpret_cast<float4*>(w1s);
#pragma unroll
        for (int q = 0; q < 4; ++q) dst[t + 256 * q] = src[t + 256 * q];
    }

    // ---- stage 64 f-rows coalesced into padded LDS tile ----
    const int base = blockIdx.x * TR;
#pragma unroll
    for (int q = 0; q < 8; ++q) {
        int i4 = t + 256 * q;              // float4 idx 0..2047
        int r  = i4 >> 5;                  // 32 float4 per row
        int c4 = i4 & 31;
        float4 v = make_float4(0.f, 0.f, 0.f, 0.f);
        if (base + r < N)
            v = reinterpret_cast<const float4*>(f + (size_t)(base + r) * FDIM)[c4];
        *reinterpret_cast<float4*>(&tile[r * TSTR + c4 * 4]) = v;
    }
    __syncthreads();

    // ---- compute: wave w -> 8 cols of A or B; lane -> row ----
    const int lane    = t & 63;
    const int w       = t >> 6;                  // 0..3
    const int colbase = (w & 1) * 8;             // cols 0-7 / 8-15
    const int isB     = w >> 1;                  // 0: A (W1 rows 0-127), 1: B
    const float* wbase = &w1s[(isB * FDIM) * L1OUT + colbase];

    float acc[8];
#pragma unroll
    for (int c = 0; c < 8; ++c) acc[c] = isB ? 0.f : b1[colbase + c];  // fold b1

    const float* trow = &tile[lane * TSTR];
#pragma unroll 2
    for (int k4 = 0; k4 < FDIM / 4; ++k4) {
        float4 xv = *reinterpret_cast<const float4*>(trow + k4 * 4);  // ds_read_b128
#pragma unroll
        for (int u = 0; u < 4; ++u) {
            float x = (u == 0) ? xv.x : (u == 1) ? xv.y : (u == 2) ? xv.z : xv.w;
            const float* wr = wbase + (size_t)(k4 * 4 + u) * L1OUT;
            float4 w0  = *reinterpret_cast<const float4*>(wr);   // uniform ds_read_b128
            float4 w1v = *reinterpret_cast<const float4*>(wr + 4);
            acc[0] += x * w0.x;  acc[1] += x * w0.y;
            acc[2] += x * w0.z;  acc[3] += x * w0.w;
            acc[4] += x * w1v.x; acc[5] += x * w1v.y;
            acc[6] += x * w1v.z; acc[7] += x * w1v.w;
        }
    }

    int n = base + lane;
    if (n < N) {
        __align__(16) __half2 h[4];
#pragma unroll
        for (int q = 0; q < 4; ++q)
            h[q] = __floats2half2_rn(acc[2 * q], acc[2 * q + 1]);
        H16* arr = isB ? B : A;                  // global-pointer select: safe
        float4* dst = reinterpret_cast<float4*>(
            reinterpret_cast<char*>(arr + n) + (w & 1) * 16);
        *dst = *reinterpret_cast<float4*>(h);
    }
}

// ============================================================================
// K2: per-edge MLP -> exp -> segment-sum. ONE edge per thread — the R3-measured
// clean configuration (64 VGPR, no scratch). 2-edge/thread with LDS weights
// spills ~1.6KB/thread (R5/R6: 658 MB scratch WRITE) — do not revisit without
// SGPR-resident weights. Weights in LDS (stride-20 rows, 16B-aligned).
// Softmax max-pass removed: identical ratios; |e_val| <~ 15 (fp32-safe).
// ============================================================================
__global__ void edge_mlp(
    const int* __restrict__ ind, const float* __restrict__ val,
    const H16* __restrict__ A, const H16* __restrict__ B,
    const float* __restrict__ deg,
    const float* __restrict__ W2, const float* __restrict__ b2,
    const float* __restrict__ Wc, const float* __restrict__ bc,
    float* __restrict__ eout, float* __restrict__ ssum, int E)
{
    __shared__ float w2s[L2DIM * 20];   // row c at w2s[c*20], 16B-aligned
    __shared__ float b2s[L2DIM];
    __shared__ float wcs[L2DIM];
    __shared__ float bc0s;

    const int t = threadIdx.x;
    for (int idx = t; idx < L2DIM * L2DIM; idx += 512) {
        int c = idx / L2DIM, r = idx - c * L2DIM;
        w2s[c * 20 + r] = W2[idx];
    }
    if (t < L2DIM) b2s[t] = b2[t];
    if (t < L2DIM) wcs[t] = Wc[t];
    if (t == 0)    bc0s   = bc[0];
    __syncthreads();

    const int e = blockIdx.x * 512 + t;
    if (e >= E) return;

    int   i = ind[e];
    int   j = ind[E + e];
    H16   a  = A[i];                     // 2x global_load_dwordx4 gather
    H16   bb = B[j];
    float v  = val[e];
    float dg = deg[i];

    float x[L2DIM];
#pragma unroll
    for (int q = 0; q < 8; ++q) {
        float2 fa = __half22float2(a.h[q]);
        float2 fb = __half22float2(bb.h[q]);
        x[2 * q]     = lrelu(fa.x + fb.x);       // b1 pre-folded into A
        x[2 * q + 1] = lrelu(fa.y + fb.y);
    }
    x[L1OUT] = fabsf(v) / dg;

    float acc[L2DIM];
#pragma unroll
    for (int r = 0; r < L2DIM; ++r) acc[r] = b2s[r];
#pragma unroll
    for (int c = 0; c < L2DIM; ++c) {
        float xc = x[c];
        const float4* r4 = reinterpret_cast<const float4*>(&w2s[c * 20]);
        float4 w0 = r4[0], w1v = r4[1], w2v = r4[2], w3 = r4[3];
        float  w16 = w2s[c * 20 + 16];
        acc[0]  += xc * w0.x;  acc[1]  += xc * w0.y;
        acc[2]  += xc * w0.z;  acc[3]  += xc * w0.w;
        acc[4]  += xc * w1v.x; acc[5]  += xc * w1v.y;
        acc[6]  += xc * w1v.z; acc[7]  += xc * w1v.w;
        acc[8]  += xc * w2v.x; acc[9]  += xc * w2v.y;
        acc[10] += xc * w2v.z; acc[11] += xc * w2v.w;
        acc[12] += xc * w3.x;  acc[13] += xc * w3.y;
        acc[14] += xc * w3.z;  acc[15] += xc * w3.w;
        acc[16] += xc * w16;
    }
    float ev = bc0s;
#pragma unroll
    for (int r = 0; r < L2DIM; ++r) ev += lrelu(acc[r]) * wcs[r];

    float ex = __expf(ev);
    eout[e] = ex;
    atomicAdd(&ssum[i], ex);
}

// ============================================================================
// K3: out = ex / s[i], 4 edges/thread vectorized
// ============================================================================
__global__ void normalize(const int* __restrict__ ind_i, const float* __restrict__ ssum,
                          float* __restrict__ ex, int E) {
    int t = blockIdx.x * blockDim.x + threadIdx.x;
    int e = t * 4;
    if (e + 3 < E) {
        int4   ii = *reinterpret_cast<const int4*>(ind_i + e);
        float4 vv = *reinterpret_cast<const float4*>(ex + e);
        vv.x /= ssum[ii.x];
        vv.y /= ssum[ii.y];
        vv.z /= ssum[ii.z];
        vv.w /= ssum[ii.w];
        *reinterpret_cast<float4*>(ex + e) = vv;
    } else {
        for (; e < E; ++e) ex[e] = ex[e] / ssum[ind_i[e]];
    }
}

extern "C" void kernel_launch(void* const* d_in, const int* in_sizes, int n_in,
                              void* d_out, int out_size, void* d_ws, size_t ws_size,
                              hipStream_t stream) {
    const int*   Jt_ind = (const int*)  d_in[0];   // [2,E]
    const float* Jt_val = (const float*)d_in[1];   // [E]
    const float* f      = (const float*)d_in[2];   // [N,128]
    const float* W1 = (const float*)d_in[4];       // [256,16]
    const float* b1 = (const float*)d_in[5];       // [16]
    const float* W2 = (const float*)d_in[6];       // [17,17]
    const float* b2 = (const float*)d_in[7];       // [17]
    const float* Wc = (const float*)d_in[8];       // [17,1]
    const float* bc = (const float*)d_in[9];       // [1]

    const int E = in_sizes[1];
    const int N = in_sizes[2] / FDIM;
    float* out = (float*)d_out;                    // [E] fp32

    // workspace: deg[N] | ssum[N] (contiguous -> one memset) | A[N] | B[N]
    char* ws = (char*)d_ws;
    float* deg  = (float*)ws;  ws += (size_t)N * sizeof(float);
    float* ssum = (float*)ws;  ws += (size_t)N * sizeof(float);
    H16*   A    = (H16*)ws;    ws += (size_t)N * sizeof(H16);
    H16*   Bm   = (H16*)ws;    ws += (size_t)N * sizeof(H16);

    const int B256 = 256;
    const int B512 = 512;
    const int nblk = (N + TR - 1) / TR;                     // node tiles
    const int eblk = (E + B512 - 1) / B512;                 // 1 edge/thread
    const int qblk = ((E + 3) / 4 + B256 - 1) / B256;       // 4 edges/thread

    hipMemsetAsync(deg, 0, 2 * (size_t)N * sizeof(float), stream);
    node_transform<<<nblk, B256, 0, stream>>>(f, W1, b1, Jt_ind, Jt_val,
                                              A, Bm, deg, N, E);
    edge_mlp      <<<eblk, B512, 0, stream>>>(Jt_ind, Jt_val, A, Bm, deg,
                                              W2, b2, Wc, bc, out, ssum, E);
    normalize     <<<qblk, B256, 0, stream>>>(Jt_ind, ssum, out, E);
}

// Round 9
// 211.299 us; speedup vs baseline: 2.9397x; 1.0557x over previous
//
#include <hip/hip_runtime.h>
#include <hip/hip_fp16.h>
#include <math.h>

#define FDIM  128
#define L1OUT 16
#define L2DIM 17
#define TRM   128     // f-rows per block in node_transform (MFMA version)
#define HSTR  136     // LDS tile row stride in halves (272 B: 2-way-only conflicts)

typedef _Float16 f16x8 __attribute__((ext_vector_type(8)));   // MFMA A/B frag (4 VGPR)
typedef float    f32x4 __attribute__((ext_vector_type(4)));   // MFMA C/D frag

// one 32-byte fp16 node row (16 halves); align 16 -> 2x global_load_dwordx4
struct __align__(16) H16 { __half2 h[8]; };

__device__ __forceinline__ float lrelu(float v) { return v >= 0.f ? v : 0.1f * v; }

// ============================================================================
// K1 (MFMA): [A|B] = f @ W'  where W'[k][c] = W1[k][c] (c<16) / W1[128+k][c-16].
// M=100k, K=128, N=32 -> mfma_f32_16x16x32_f16, 2 N-tiles (nt=0 -> A, 1 -> B).
// R8 lesson: VALU version needs 256 uniform ds_read_b128/wave for W1 (~35 us
// LDS-pipe floor). MFMA holds W' frags in 32 VGPRs (loaded once/block from
// L2-hot W1) and reads f-frags as 8 ds_read_b128/wave/subtile -> ~20x fewer
// LDS ops. f staged as fp16 (A/B outputs were already fp16; error budget ok).
// Layouts (HW-verified per guide): A-frag A[m=lane&15][k=(lane>>4)*8+j];
// B-frag B[k=(lane>>4)*8+j][n=lane&15]; C/D col=lane&15, row=(lane>>4)*4+reg.
// + degree atomics folded in (deg zeroed by memsetAsync before this kernel).
// ============================================================================
__global__ void node_transform(
    const float* __restrict__ f, const float* __restrict__ W1,
    const float* __restrict__ b1,
    const int* __restrict__ ind_i, const float* __restrict__ val,
    H16* __restrict__ A, H16* __restrict__ B,
    float* __restrict__ deg, int N, int E)
{
    __shared__ __align__(16) _Float16 tile[TRM * HSTR];   // 34.8 KB

    const int t    = threadIdx.x;
    const int gtid = blockIdx.x * 256 + t;
    const int GT   = gridDim.x * 256;

    // ---- degree atomics (4 edges/thread, grid-stride, fire-and-forget) ----
    {
        const int E4 = E >> 2;
        for (int q = gtid; q < E4; q += GT) {
            int e = q << 2;
            int4   ii = *reinterpret_cast<const int4*>(ind_i + e);
            float4 vv = *reinterpret_cast<const float4*>(val + e);
            atomicAdd(&deg[ii.x], fabsf(vv.x));
            atomicAdd(&deg[ii.y], fabsf(vv.y));
            atomicAdd(&deg[ii.z], fabsf(vv.z));
            atomicAdd(&deg[ii.w], fabsf(vv.w));
        }
        if (gtid < (E & 3)) {
            int e = (E & ~3) + gtid;
            atomicAdd(&deg[ind_i[e]], fabsf(val[e]));
        }
    }

    const int lane = t & 63;
    const int wv   = t >> 6;          // wave 0..3
    const int n    = lane & 15;       // MFMA matrix-dim index (col)
    const int quad = lane >> 4;       // k-block / row-group selector

    // ---- load W' B-frags once per block: bfr[nt][ks], k = 32*ks + 8*quad + j
    f16x8 bfr[2][4];
#pragma unroll
    for (int nt = 0; nt < 2; ++nt)
#pragma unroll
        for (int ks = 0; ks < 4; ++ks) {
            f16x8 bf;
#pragma unroll
            for (int j = 0; j < 8; ++j) {
                int k = 32 * ks + 8 * quad + j;
                bf[j] = (_Float16)W1[(size_t)(nt * FDIM + k) * L1OUT + n];
            }
            bfr[nt][ks] = bf;
        }
    float b1v = b1[n];                // folded into nt=0 accumulator init

    // ---- stage 128 f-rows as fp16 into padded LDS tile (coalesced) ----
    const int base = blockIdx.x * TRM;
#pragma unroll
    for (int q = 0; q < 8; ++q) {
        int p  = t + 256 * q;         // half8-chunk index 0..2047
        int r  = p >> 4;              // 16 chunks per row
        int c8 = p & 15;              // chunk within row (8 halves)
        float4 lo = make_float4(0.f, 0.f, 0.f, 0.f);
        float4 hi = lo;
        if (base + r < N) {
            const float4* src = reinterpret_cast<const float4*>(
                f + (size_t)(base + r) * FDIM + c8 * 8);
            lo = src[0];
            hi = src[1];
        }
        f16x8 hx;
        hx[0] = (_Float16)lo.x; hx[1] = (_Float16)lo.y;
        hx[2] = (_Float16)lo.z; hx[3] = (_Float16)lo.w;
        hx[4] = (_Float16)hi.x; hx[5] = (_Float16)hi.y;
        hx[6] = (_Float16)hi.z; hx[7] = (_Float16)hi.w;
        *reinterpret_cast<f16x8*>(&tile[r * HSTR + c8 * 8]) = hx;
    }
    __syncthreads();

    // ---- compute: wave wv handles M-subtiles wv and wv+4 (16 rows each) ----
#pragma unroll
    for (int si = 0; si < 2; ++si) {
        const int m0 = (wv + 4 * si) * 16;
        f32x4 acc0 = { b1v, b1v, b1v, b1v };      // A-cols + b1
        f32x4 acc1 = { 0.f, 0.f, 0.f, 0.f };      // B-cols
#pragma unroll
        for (int ks = 0; ks < 4; ++ks) {
            // A-frag: row m0+n, k = 32*ks + 8*quad .. +7  (one ds_read_b128)
            f16x8 af = *reinterpret_cast<const f16x8*>(
                &tile[(m0 + n) * HSTR + 32 * ks + 8 * quad]);
            acc0 = __builtin_amdgcn_mfma_f32_16x16x32_f16(af, bfr[0][ks], acc0, 0, 0, 0);
            acc1 = __builtin_amdgcn_mfma_f32_16x16x32_f16(af, bfr[1][ks], acc1, 0, 0, 0);
        }
        // epilogue: D col = n, rows = m0 + quad*4 + reg
#pragma unroll
        for (int reg = 0; reg < 4; ++reg) {
            int node = base + m0 + quad * 4 + reg;
            if (node < N) {
                reinterpret_cast<_Float16*>(A + node)[n] = (_Float16)acc0[reg];
                reinterpret_cast<_Float16*>(B + node)[n] = (_Float16)acc1[reg];
            }
        }
    }
}

// ============================================================================
// K2: per-edge MLP -> exp -> segment-sum. ONE edge per thread — the R3-measured
// clean configuration (64 VGPR, no scratch). 2-edge/thread with LDS weights
// spills ~1.6KB/thread (R5/R6: 658 MB scratch WRITE) — do not revisit without
// SGPR-resident weights. Weights in LDS (stride-20 rows, 16B-aligned).
// Softmax max-pass removed: identical ratios; |e_val| <~ 15 (fp32-safe).
// ============================================================================
__global__ void edge_mlp(
    const int* __restrict__ ind, const float* __restrict__ val,
    const H16* __restrict__ A, const H16* __restrict__ B,
    const float* __restrict__ deg,
    const float* __restrict__ W2, const float* __restrict__ b2,
    const float* __restrict__ Wc, const float* __restrict__ bc,
    float* __restrict__ eout, float* __restrict__ ssum, int E)
{
    __shared__ float w2s[L2DIM * 20];   // row c at w2s[c*20], 16B-aligned
    __shared__ float b2s[L2DIM];
    __shared__ float wcs[L2DIM];
    __shared__ float bc0s;

    const int t = threadIdx.x;
    for (int idx = t; idx < L2DIM * L2DIM; idx += 512) {
        int c = idx / L2DIM, r = idx - c * L2DIM;
        w2s[c * 20 + r] = W2[idx];
    }
    if (t < L2DIM) b2s[t] = b2[t];
    if (t < L2DIM) wcs[t] = Wc[t];
    if (t == 0)    bc0s   = bc[0];
    __syncthreads();

    const int e = blockIdx.x * 512 + t;
    if (e >= E) return;

    int   i = ind[e];
    int   j = ind[E + e];
    H16   a  = A[i];                     // 2x global_load_dwordx4 gather
    H16   bb = B[j];
    float v  = val[e];
    float dg = deg[i];

    float x[L2DIM];
#pragma unroll
    for (int q = 0; q < 8; ++q) {
        float2 fa = __half22float2(a.h[q]);
        float2 fb = __half22float2(bb.h[q]);
        x[2 * q]     = lrelu(fa.x + fb.x);       // b1 pre-folded into A
        x[2 * q + 1] = lrelu(fa.y + fb.y);
    }
    x[L1OUT] = fabsf(v) / dg;

    float acc[L2DIM];
#pragma unroll
    for (int r = 0; r < L2DIM; ++r) acc[r] = b2s[r];
#pragma unroll
    for (int c = 0; c < L2DIM; ++c) {
        float xc = x[c];
        const float4* r4 = reinterpret_cast<const float4*>(&w2s[c * 20]);
        float4 w0 = r4[0], w1v = r4[1], w2v = r4[2], w3 = r4[3];
        float  w16 = w2s[c * 20 + 16];
        acc[0]  += xc * w0.x;  acc[1]  += xc * w0.y;
        acc[2]  += xc * w0.z;  acc[3]  += xc * w0.w;
        acc[4]  += xc * w1v.x; acc[5]  += xc * w1v.y;
        acc[6]  += xc * w1v.z; acc[7]  += xc * w1v.w;
        acc[8]  += xc * w2v.x; acc[9]  += xc * w2v.y;
        acc[10] += xc * w2v.z; acc[11] += xc * w2v.w;
        acc[12] += xc * w3.x;  acc[13] += xc * w3.y;
        acc[14] += xc * w3.z;  acc[15] += xc * w3.w;
        acc[16] += xc * w16;
    }
    float ev = bc0s;
#pragma unroll
    for (int r = 0; r < L2DIM; ++r) ev += lrelu(acc[r]) * wcs[r];

    float ex = __expf(ev);
    eout[e] = ex;
    atomicAdd(&ssum[i], ex);
}

// ============================================================================
// K3: out = ex / s[i], 4 edges/thread vectorized
// ============================================================================
__global__ void normalize(const int* __restrict__ ind_i, const float* __restrict__ ssum,
                          float* __restrict__ ex, int E) {
    int t = blockIdx.x * blockDim.x + threadIdx.x;
    int e = t * 4;
    if (e + 3 < E) {
        int4   ii = *reinterpret_cast<const int4*>(ind_i + e);
        float4 vv = *reinterpret_cast<const float4*>(ex + e);
        vv.x /= ssum[ii.x];
        vv.y /= ssum[ii.y];
        vv.z /= ssum[ii.z];
        vv.w /= ssum[ii.w];
        *reinterpret_cast<float4*>(ex + e) = vv;
    } else {
        for (; e < E; ++e) ex[e] = ex[e] / ssum[ind_i[e]];
    }
}

extern "C" void kernel_launch(void* const* d_in, const int* in_sizes, int n_in,
                              void* d_out, int out_size, void* d_ws, size_t ws_size,
                              hipStream_t stream) {
    const int*   Jt_ind = (const int*)  d_in[0];   // [2,E]
    const float* Jt_val = (const float*)d_in[1];   // [E]
    const float* f      = (const float*)d_in[2];   // [N,128]
    const float* W1 = (const float*)d_in[4];       // [256,16]
    const float* b1 = (const float*)d_in[5];       // [16]
    const float* W2 = (const float*)d_in[6];       // [17,17]
    const float* b2 = (const float*)d_in[7];       // [17]
    const float* Wc = (const float*)d_in[8];       // [17,1]
    const float* bc = (const float*)d_in[9];       // [1]

    const int E = in_sizes[1];
    const int N = in_sizes[2] / FDIM;
    float* out = (float*)d_out;                    // [E] fp32

    // workspace: deg[N] | ssum[N] (contiguous -> one memset) | A[N] | B[N]
    char* ws = (char*)d_ws;
    float* deg  = (float*)ws;  ws += (size_t)N * sizeof(float);
    float* ssum = (float*)ws;  ws += (size_t)N * sizeof(float);
    H16*   A    = (H16*)ws;    ws += (size_t)N * sizeof(H16);
    H16*   Bm   = (H16*)ws;    ws += (size_t)N * sizeof(H16);

    const int B256 = 256;
    const int B512 = 512;
    const int nblk = (N + TRM - 1) / TRM;                   // node tiles (128 rows)
    const int eblk = (E + B512 - 1) / B512;                 // 1 edge/thread
    const int qblk = ((E + 3) / 4 + B256 - 1) / B256;       // 4 edges/thread

    hipMemsetAsync(deg, 0, 2 * (size_t)N * sizeof(float), stream);
    node_transform<<<nblk, B256, 0, stream>>>(f, W1, b1, Jt_ind, Jt_val,
                                              A, Bm, deg, N, E);
    edge_mlp      <<<eblk, B512, 0, stream>>>(Jt_ind, Jt_val, A, Bm, deg,
                                              W2, b2, Wc, bc, out, ssum, E);
    normalize     <<<qblk, B256, 0, stream>>>(Jt_ind, ssum, out, E);
}